// Round 12
// baseline (2757.538 us; speedup 1.0000x reference)
//
#include <hip/hip_runtime.h>
#include <math.h>

namespace {

typedef short short8 __attribute__((ext_vector_type(8)));
typedef float f32x16 __attribute__((ext_vector_type(16)));
typedef unsigned int u32;

constexpr int NEX = 256, LLEN = 2048, FEATS = 8192;
constexpr int PL = 512;          // 4*Dmax zeros on the left
constexpr int XSZ = 4096;

// packed bf16 split: (lo_bf16 << 16) | hi_bf16, both RNE
__device__ __forceinline__ u32 bfsplit(float x) {
  u32 b = __float_as_uint(x);
  u32 hb = (b + 0x7fffu + ((b >> 16) & 1u)) >> 16;
  float lo = x - __uint_as_float(hb << 16);
  u32 b2 = __float_as_uint(lo);
  u32 lb = (b2 + 0x7fffu + ((b2 >> 16) & 1u)) >> 16;
  return hb | (lb << 16);
}

__device__ __forceinline__ float max8(const float* v, int o) {
  float m0 = fmaxf(fmaxf(v[o+0], v[o+1]), v[o+2]);
  float m1 = fmaxf(fmaxf(v[o+3], v[o+4]), v[o+5]);
  float m2 = fmaxf(v[o+6], v[o+7]);
  return fmaxf(fmaxf(m0, m1), m2);
}
__device__ __forceinline__ float min8(const float* v, int o) {
  float m0 = fminf(fminf(v[o+0], v[o+1]), v[o+2]);
  float m1 = fminf(fminf(v[o+3], v[o+4]), v[o+5]);
  float m2 = fminf(v[o+6], v[o+7]);
  return fminf(fminf(m0, m1), m2);
}

#define MFMA __builtin_amdgcn_mfma_f32_32x32x16_bf16

template<int D, int DI>
__device__ __forceinline__ void body(
    const float* __restrict__ X, const float* __restrict__ W,
    float* __restrict__ out, u32* __restrict__ xhl,
    float* __restrict__ binsM, float* __restrict__ binsN,
    float* __restrict__ fin)
{
  const int n = blockIdx.x, diff = blockIdx.y, tid = threadIdx.x;
  const int lane = tid & 63, wave = tid >> 6;
  const int col = lane & 31, hi = lane >> 5;

  // ---- stage padded input as packed bf16 hi/lo (diff on the fly) ----
  const float* xr = X + n * LLEN;
  for (int i = tid; i < XSZ; i += 256) {
    float x = 0.f;
    if (diff) { if (i >= PL && i < PL + LLEN - 1) x = xr[i - PL + 1] - xr[i - PL]; }
    else      { if (i >= PL && i < PL + LLEN)     x = xr[i - PL]; }
    xhl[i] = bfsplit(x);
  }

  // ---- lane-private bins, bank-invariant layout [wave][bin][lane] ----
  // addr = wave*1024 + b*64 + lane -> bank = lane%32 for EVERY bin value:
  // the wave access is always exactly 2 lanes/bank (free), data-independent.
  float* myM = binsM + wave * 1024 + lane;
  float* myN = binsN + wave * 1024 + lane;
  #pragma unroll
  for (int b = 0; b < 16; ++b) { myM[b * 64] = 0.f; myN[b * 64] = 0.f; }
  __syncthreads();

  const float* wall = W + (DI * 2 + diff) * (256 * 9);

  // Permuted A-row -> kernel map: lane owns two complete 8-k groups.
  // row r holds kernel g*8+k, g = 2*(r>>4)+((r>>2)&1), k = (r&3)+4*((r>>3)&1).
  // c[0..7] -> local kerns 8*hi+0..7 (bin 0..7); c[8..15] -> +16 (bin 8..15).
  const int g_of_r = ((col >> 4) << 1) | ((col >> 2) & 1);
  const int k_of_r = (col & 3) | (((col >> 3) & 1) << 2);
  const int kloc = g_of_r * 8 + k_of_r;

  const f32x16 czero = {};

  for (int kt2 = 0; kt2 < 2; ++kt2) {
    // A fragments for this 32-kern tile (taps padded 9->16 with zeros)
    short8 ah, al;
    {
      const float* wrow = wall + (wave * 64 + kt2 * 32 + kloc) * 9;
      #pragma unroll
      for (int e = 0; e < 8; ++e) {
        int j = hi * 8 + e;
        float wv = (j < 9) ? wrow[j] : 0.f;
        u32 p = bfsplit(wv);
        ah[e] = (short)(p & 0xffffu);
        al[e] = (short)(p >> 16);
      }
    }

    #pragma clang loop unroll_count(1)
    for (int tt = 0; tt < 64; ++tt) {
      // B fragment: B[j=8*hi+e][col] = x[tt*32 + col + (j-4)*D]
      const int ebase = PL + tt * 32 + col + (hi * 8 - 4) * D;
      u32 uu[8];
      #pragma unroll
      for (int e = 0; e < 8; ++e) uu[e] = xhl[ebase + e * D];
      union { short8 s; u32 u[4]; } bh, bl;
      #pragma unroll
      for (int p = 0; p < 4; ++p) {
        bh.u[p] = __builtin_amdgcn_perm(uu[2*p+1], uu[2*p], 0x05040100u);
        bl.u[p] = __builtin_amdgcn_perm(uu[2*p+1], uu[2*p], 0x07060302u);
      }

      // (wh+wl)(xh+xl) ~= wl*xh + wh*xl + wh*xh (lo*lo dropped)
      f32x16 c;
      c = MFMA(al, bh.s, czero, 0, 0, 0);
      c = MFMA(ah, bl.s, c,     0, 0, 0);
      c = MFMA(ah, bh.s, c,     0, 0, 0);

      // Embed k-index in low 4 mantissa bits: values become distinct,
      // max/min then carries its own argindex (error <= 16 ulp).
      float cf[16];
      #pragma unroll
      for (int i = 0; i < 16; ++i)
        cf[i] = __uint_as_float((__float_as_uint(c[i]) & 0xFFFFFFF0u) |
                                (u32)(i & 7));

      const float zx0 = max8(cf, 0), zn0 = min8(cf, 0);
      const float zx1 = max8(cf, 8), zn1 = min8(cf, 8);
      const u32 kx0 = __float_as_uint(zx0) & 7u;
      const u32 kn0 = __float_as_uint(zn0) & 7u;
      const u32 kx1 = __float_as_uint(zx1) & 7u;
      const u32 kn1 = __float_as_uint(zn1) & 7u;

      // Fire-and-forget ds_add_f32 (no return): 1 DS op per accumulate,
      // no RMW latency chain, no bank conflicts (layout above).
      atomicAdd(&myM[kx0 * 64],        zx0);
      atomicAdd(&myM[(8 + kx1) * 64],  zx1);
      atomicAdd(&myN[kn0 * 64],        1.f);
      atomicAdd(&myN[(8 + kn1) * 64],  1.f);
    }

    // ---- flush: lanes 0..31 reduce M, lanes 32..63 reduce N ----
    // local kern s = 8*hi_s + 16*chunk + k  ->  bin b = chunk*8 + k of
    // lanes (col, hi_s) for all col.
    {
      const int s = lane & 31;
      const int hi_s = (s >> 3) & 1;
      const int b = ((s >> 4) << 3) | (s & 7);
      const float* src =
          (lane < 32 ? binsM : binsN) + wave * 1024 + b * 64 + 32 * hi_s;
      float acc = 0.f;
      #pragma unroll
      for (int c2 = 0; c2 < 32; ++c2) acc += src[c2];   // stride-1: clean
      fin[((wave * 32 + s) * 2 + kt2) * 2 + (lane >= 32 ? 1 : 0)] = acc;
    }

    // rezero own bins for next round (same-wave DS is in-order: safe)
    if (kt2 == 0) {
      #pragma unroll
      for (int b = 0; b < 16; ++b) { myM[b * 64] = 0.f; myN[b * 64] = 0.f; }
    }
  }
  __syncthreads();

  // ---- final: tid = kern (single owner) ----
  const int w2 = tid >> 6, kt2f = (tid >> 5) & 1, r = tid & 31;
  float M = fin[((w2 * 32 + r) * 2 + kt2f) * 2 + 0];
  float N = fin[((w2 * 32 + r) * 2 + kt2f) * 2 + 1];

  if (diff) {
    // remove the spurious t=2047 column (diff branch has 2047 timesteps)
    const float* wrow = wall + tid * 9;
    float z = 0.f;
    #pragma unroll
    for (int j = 0; j < 9; ++j) {
      u32 u = xhl[PL + (LLEN - 1) + (j - 4) * D];
      float xh = __uint_as_float((u & 0xffffu) << 16);
      float xl = __uint_as_float((u >> 16) << 16);
      u32 wp = bfsplit(wrow[j]);
      float wh = __uint_as_float((wp & 0xffffu) << 16);
      float wl = __uint_as_float((wp >> 16) << 16);
      z += wh * xh + wh * xl + wl * xh;
    }
    float* zrow = binsM;               // bins are dead now; reuse as scratch
    zrow[tid] = z;
    __syncthreads();
    const int h8 = tid & ~7;
    float zxv = zrow[h8], znv = zrow[h8];
    #pragma unroll
    for (int j = 1; j < 8; ++j) {
      zxv = fmaxf(zxv, zrow[h8 + j]);
      znv = fminf(znv, zrow[h8 + j]);
    }
    M -= (z == zxv) ? z : 0.f;
    N -= (z == znv) ? 1.f : 0.f;
  }

  const int base = n * FEATS + (DI * 4 + diff * 2) * 256 + tid;
  out[base]       = M > 0.f ? sqrtf(M) : 0.f;    // count_max
  out[base + 256] = N > 0.f ? sqrtf(N) : 0.f;    // count_min
}

__global__ __launch_bounds__(256, 3) void hydra_kernel(
    const float* __restrict__ X, const float* __restrict__ W,
    float* __restrict__ out)
{
  __shared__ u32   xhl[XSZ];               // 16 KB packed bf16 hi|lo
  __shared__ float binsM[4 * 16 * 64];     // 16 KB [wave][bin][lane]
  __shared__ float binsN[4 * 16 * 64];     // 16 KB [wave][bin][lane]
  __shared__ float fin[1024];              // 4 KB: [4][32][2]{M,N}
  // total 53248 B <= 54613 -> 3 blocks/CU
  switch (blockIdx.z) {
    case 0: body<1,   0>(X, W, out, xhl, binsM, binsN, fin); break;
    case 1: body<2,   1>(X, W, out, xhl, binsM, binsN, fin); break;
    case 2: body<4,   2>(X, W, out, xhl, binsM, binsN, fin); break;
    case 3: body<8,   3>(X, W, out, xhl, binsM, binsN, fin); break;
    case 4: body<16,  4>(X, W, out, xhl, binsM, binsN, fin); break;
    case 5: body<32,  5>(X, W, out, xhl, binsM, binsN, fin); break;
    case 6: body<64,  6>(X, W, out, xhl, binsM, binsN, fin); break;
    case 7: body<128, 7>(X, W, out, xhl, binsM, binsN, fin); break;
  }
}

} // namespace

extern "C" void kernel_launch(void* const* d_in, const int* in_sizes, int n_in,
                              void* d_out, int out_size, void* d_ws, size_t ws_size,
                              hipStream_t stream) {
  const float* X = (const float*)d_in[0];
  const float* W = (const float*)d_in[1];
  float* out = (float*)d_out;
  dim3 grid(NEX, 2, 8);
  hipLaunchKernelGGL(hydra_kernel, grid, dim3(256), 0, stream, X, W, out);
}

// Round 13
// 304.803 us; speedup vs baseline: 9.0469x; 9.0469x over previous
//
#include <hip/hip_runtime.h>
#include <math.h>

namespace {

typedef short short8 __attribute__((ext_vector_type(8)));
typedef float f32x16 __attribute__((ext_vector_type(16)));
typedef unsigned int u32;

constexpr int NEX = 256, LLEN = 2048, FEATS = 8192;
constexpr int PL = 512;          // 4*Dmax zeros on the left
constexpr int XSZ = 4096;

// packed bf16 split: (lo_bf16 << 16) | hi_bf16, both RNE
__device__ __forceinline__ u32 bfsplit(float x) {
  u32 b = __float_as_uint(x);
  u32 hb = (b + 0x7fffu + ((b >> 16) & 1u)) >> 16;
  float lo = x - __uint_as_float(hb << 16);
  u32 b2 = __float_as_uint(lo);
  u32 lb = (b2 + 0x7fffu + ((b2 >> 16) & 1u)) >> 16;
  return hb | (lb << 16);
}

__device__ __forceinline__ float max8(const float* v, int o) {
  float m0 = fmaxf(fmaxf(v[o+0], v[o+1]), v[o+2]);
  float m1 = fmaxf(fmaxf(v[o+3], v[o+4]), v[o+5]);
  float m2 = fmaxf(v[o+6], v[o+7]);
  return fmaxf(fmaxf(m0, m1), m2);
}
__device__ __forceinline__ float min8(const float* v, int o) {
  float m0 = fminf(fminf(v[o+0], v[o+1]), v[o+2]);
  float m1 = fminf(fminf(v[o+3], v[o+4]), v[o+5]);
  float m2 = fminf(v[o+6], v[o+7]);
  return fminf(fminf(m0, m1), m2);
}

#define MFMA __builtin_amdgcn_mfma_f32_32x32x16_bf16

template<int D, int DI>
__device__ __forceinline__ void body(
    const float* __restrict__ X, const float* __restrict__ W,
    float* __restrict__ out, u32* __restrict__ xhl,
    float* __restrict__ binsM, float* __restrict__ binsN,
    float* __restrict__ fin)
{
  const int n = blockIdx.x, diff = blockIdx.y, tid = threadIdx.x;
  const int lane = tid & 63, wave = tid >> 6;
  const int col = lane & 31, hi = lane >> 5;

  // ---- stage padded input as packed bf16 hi/lo (diff on the fly) ----
  const float* xr = X + n * LLEN;
  for (int i = tid; i < XSZ; i += 256) {
    float x = 0.f;
    if (diff) { if (i >= PL && i < PL + LLEN - 1) x = xr[i - PL + 1] - xr[i - PL]; }
    else      { if (i >= PL && i < PL + LLEN)     x = xr[i - PL]; }
    xhl[i] = bfsplit(x);
  }

  // ---- lane-private bins, bank-invariant layout [wave][bin][lane] ----
  // addr = wave*1024 + b*64 + lane -> bank = lane%32 for EVERY bin value:
  // always exactly 2 lanes/bank (free), independent of the data-chosen bin.
  float* myM = binsM + wave * 1024 + lane;
  float* myN = binsN + wave * 1024 + lane;
  #pragma unroll
  for (int b = 0; b < 16; ++b) { myM[b * 64] = 0.f; myN[b * 64] = 0.f; }
  __syncthreads();

  const float* wall = W + (DI * 2 + diff) * (256 * 9);

  // Permuted A-row -> kernel map: lane owns two complete 8-k groups.
  // row r holds kernel g*8+k, g = 2*(r>>4)+((r>>2)&1), k = (r&3)+4*((r>>3)&1).
  // c[0..7] -> local kerns 8*hi+0..7 (bin 0..7); c[8..15] -> +16 (bin 8..15).
  const int g_of_r = ((col >> 4) << 1) | ((col >> 2) & 1);
  const int k_of_r = (col & 3) | (((col >> 3) & 1) << 2);
  const int kloc = g_of_r * 8 + k_of_r;

  const f32x16 czero = {};

  for (int kt2 = 0; kt2 < 2; ++kt2) {
    // A fragments for this 32-kern tile (taps padded 9->16 with zeros)
    short8 ah, al;
    {
      const float* wrow = wall + (wave * 64 + kt2 * 32 + kloc) * 9;
      #pragma unroll
      for (int e = 0; e < 8; ++e) {
        int j = hi * 8 + e;
        float wv = (j < 9) ? wrow[j] : 0.f;
        u32 p = bfsplit(wv);
        ah[e] = (short)(p & 0xffffu);
        al[e] = (short)(p >> 16);
      }
    }

    #pragma clang loop unroll_count(1)
    for (int tt = 0; tt < 64; ++tt) {
      // B fragment: B[j=8*hi+e][col] = x[tt*32 + col + (j-4)*D]
      const int ebase = PL + tt * 32 + col + (hi * 8 - 4) * D;
      u32 uu[8];
      #pragma unroll
      for (int e = 0; e < 8; ++e) uu[e] = xhl[ebase + e * D];
      union { short8 s; u32 u[4]; } bh, bl;
      #pragma unroll
      for (int p = 0; p < 4; ++p) {
        bh.u[p] = __builtin_amdgcn_perm(uu[2*p+1], uu[2*p], 0x05040100u);
        bl.u[p] = __builtin_amdgcn_perm(uu[2*p+1], uu[2*p], 0x07060302u);
      }

      // (wh+wl)(xh+xl) ~= wl*xh + wh*xl + wh*xh (lo*lo dropped)
      f32x16 c;
      c = MFMA(al, bh.s, czero, 0, 0, 0);
      c = MFMA(ah, bl.s, c,     0, 0, 0);
      c = MFMA(ah, bh.s, c,     0, 0, 0);

      // Embed k-index in low 4 mantissa bits: values become distinct,
      // max/min then carries its own argindex (error <= 16 ulp).
      float cf[16];
      #pragma unroll
      for (int i = 0; i < 16; ++i)
        cf[i] = __uint_as_float((__float_as_uint(c[i]) & 0xFFFFFFF0u) |
                                (u32)(i & 7));

      const float zx0 = max8(cf, 0), zn0 = min8(cf, 0);
      const float zx1 = max8(cf, 8), zn1 = min8(cf, 8);
      const u32 kx0 = __float_as_uint(zx0) & 7u;
      const u32 kn0 = __float_as_uint(zn0) & 7u;
      const u32 kx1 = __float_as_uint(zx1) & 7u;
      const u32 kn1 = __float_as_uint(zn1) & 7u;

      // Explicit non-atomic RMW (ds_read + v_add + ds_write): pipelineable,
      // lane-private so no races; bank pattern is data-independent (free).
      myM[kx0 * 64]       += zx0;
      myM[(8 + kx1) * 64] += zx1;
      myN[kn0 * 64]       += 1.f;
      myN[(8 + kn1) * 64] += 1.f;
    }

    // ---- flush: lanes 0..31 reduce M, lanes 32..63 reduce N ----
    // local kern s = 8*hi_s + 16*chunk + k  ->  bin b = chunk*8 + k of
    // lanes (col, hi_s) for all col.
    {
      const int s = lane & 31;
      const int hi_s = (s >> 3) & 1;
      const int b = ((s >> 4) << 3) | (s & 7);
      const float* src =
          (lane < 32 ? binsM : binsN) + wave * 1024 + b * 64 + 32 * hi_s;
      float acc = 0.f;
      #pragma unroll
      for (int c2 = 0; c2 < 32; ++c2) acc += src[c2];   // stride-1: clean
      fin[((wave * 32 + s) * 2 + kt2) * 2 + (lane >= 32 ? 1 : 0)] = acc;
    }

    // rezero own bins for next round (same-wave DS is in-order: safe)
    if (kt2 == 0) {
      #pragma unroll
      for (int b = 0; b < 16; ++b) { myM[b * 64] = 0.f; myN[b * 64] = 0.f; }
    }
  }
  __syncthreads();

  // ---- final: tid = kern (single owner) ----
  const int w2 = tid >> 6, kt2f = (tid >> 5) & 1, r = tid & 31;
  float M = fin[((w2 * 32 + r) * 2 + kt2f) * 2 + 0];
  float N = fin[((w2 * 32 + r) * 2 + kt2f) * 2 + 1];

  if (diff) {
    // remove the spurious t=2047 column (diff branch has 2047 timesteps)
    const float* wrow = wall + tid * 9;
    float z = 0.f;
    #pragma unroll
    for (int j = 0; j < 9; ++j) {
      u32 u = xhl[PL + (LLEN - 1) + (j - 4) * D];
      float xh = __uint_as_float((u & 0xffffu) << 16);
      float xl = __uint_as_float((u >> 16) << 16);
      u32 wp = bfsplit(wrow[j]);
      float wh = __uint_as_float((wp & 0xffffu) << 16);
      float wl = __uint_as_float((wp >> 16) << 16);
      z += wh * xh + wh * xl + wl * xh;
    }
    float* zrow = binsM;               // bins are dead now; reuse as scratch
    zrow[tid] = z;
    __syncthreads();
    const int h8 = tid & ~7;
    float zxv = zrow[h8], znv = zrow[h8];
    #pragma unroll
    for (int j = 1; j < 8; ++j) {
      zxv = fmaxf(zxv, zrow[h8 + j]);
      znv = fminf(znv, zrow[h8 + j]);
    }
    M -= (z == zxv) ? z : 0.f;
    N -= (z == znv) ? 1.f : 0.f;
  }

  const int base = n * FEATS + (DI * 4 + diff * 2) * 256 + tid;
  out[base]       = M > 0.f ? sqrtf(M) : 0.f;    // count_max
  out[base + 256] = N > 0.f ? sqrtf(N) : 0.f;    // count_min
}

__global__ __launch_bounds__(256, 3) void hydra_kernel(
    const float* __restrict__ X, const float* __restrict__ W,
    float* __restrict__ out)
{
  __shared__ u32   xhl[XSZ];               // 16 KB packed bf16 hi|lo
  __shared__ float binsM[4 * 16 * 64];     // 16 KB [wave][bin][lane]
  __shared__ float binsN[4 * 16 * 64];     // 16 KB [wave][bin][lane]
  __shared__ float fin[1024];              // 4 KB: [4][32][2]{M,N}
  // total 53248 B <= 54613 -> 3 blocks/CU
  switch (blockIdx.z) {
    case 0: body<1,   0>(X, W, out, xhl, binsM, binsN, fin); break;
    case 1: body<2,   1>(X, W, out, xhl, binsM, binsN, fin); break;
    case 2: body<4,   2>(X, W, out, xhl, binsM, binsN, fin); break;
    case 3: body<8,   3>(X, W, out, xhl, binsM, binsN, fin); break;
    case 4: body<16,  4>(X, W, out, xhl, binsM, binsN, fin); break;
    case 5: body<32,  5>(X, W, out, xhl, binsM, binsN, fin); break;
    case 6: body<64,  6>(X, W, out, xhl, binsM, binsN, fin); break;
    case 7: body<128, 7>(X, W, out, xhl, binsM, binsN, fin); break;
  }
}

} // namespace

extern "C" void kernel_launch(void* const* d_in, const int* in_sizes, int n_in,
                              void* d_out, int out_size, void* d_ws, size_t ws_size,
                              hipStream_t stream) {
  const float* X = (const float*)d_in[0];
  const float* W = (const float*)d_in[1];
  float* out = (float*)d_out;
  dim3 grid(NEX, 2, 8);
  hipLaunchKernelGGL(hydra_kernel, grid, dim3(256), 0, stream, X, W, out);
}

// Round 14
// 283.519 us; speedup vs baseline: 9.7261x; 1.0751x over previous
//
#include <hip/hip_runtime.h>
#include <math.h>

namespace {

typedef short short8 __attribute__((ext_vector_type(8)));
typedef float f32x16 __attribute__((ext_vector_type(16)));
typedef unsigned int u32;
typedef unsigned long long u64;

constexpr int NEX = 256, LLEN = 2048, FEATS = 8192;
constexpr int PL = 512;          // 4*Dmax zeros on the left
constexpr int XSZ = 4096;

// packed bf16 split: (lo_bf16 << 16) | hi_bf16, both RNE
__device__ __forceinline__ u32 bfsplit(float x) {
  u32 b = __float_as_uint(x);
  u32 hb = (b + 0x7fffu + ((b >> 16) & 1u)) >> 16;
  float lo = x - __uint_as_float(hb << 16);
  u32 b2 = __float_as_uint(lo);
  u32 lb = (b2 + 0x7fffu + ((b2 >> 16) & 1u)) >> 16;
  return hb | (lb << 16);
}

__device__ __forceinline__ float max8(const float* v, int o) {
  float m0 = fmaxf(fmaxf(v[o+0], v[o+1]), v[o+2]);
  float m1 = fmaxf(fmaxf(v[o+3], v[o+4]), v[o+5]);
  float m2 = fmaxf(v[o+6], v[o+7]);
  return fmaxf(fmaxf(m0, m1), m2);
}
__device__ __forceinline__ float min8(const float* v, int o) {
  float m0 = fminf(fminf(v[o+0], v[o+1]), v[o+2]);
  float m1 = fminf(fminf(v[o+3], v[o+4]), v[o+5]);
  float m2 = fminf(v[o+6], v[o+7]);
  return fminf(fminf(m0, m1), m2);
}

#define MFMA __builtin_amdgcn_mfma_f32_32x32x16_bf16

template<int D, int DI>
__device__ __forceinline__ void body(
    const float* __restrict__ X, const float* __restrict__ W,
    float* __restrict__ out, u32* __restrict__ xhl,
    float* __restrict__ binsM, u32* __restrict__ nw,
    float* __restrict__ fin)
{
  const int n = blockIdx.x, diff = blockIdx.y, tid = threadIdx.x;
  const int lane = tid & 63, wave = tid >> 6;
  const int col = lane & 31, hi = lane >> 5;

  // ---- stage padded input as packed bf16 hi/lo (diff on the fly) ----
  const float* xr = X + n * LLEN;
  for (int i = tid; i < XSZ; i += 256) {
    float x = 0.f;
    if (diff) { if (i >= PL && i < PL + LLEN - 1) x = xr[i - PL + 1] - xr[i - PL]; }
    else      { if (i >= PL && i < PL + LLEN)     x = xr[i - PL]; }
    xhl[i] = bfsplit(x);
  }

  // ---- lane-private M bins, bank-invariant layout [wave][bin][lane] ----
  // addr = wave*1024 + b*64 + lane -> bank = lane%32 for EVERY bin: free.
  float* myM = binsM + wave * 1024 + lane;
  #pragma unroll
  for (int b = 0; b < 16; ++b) myM[b * 64] = 0.f;
  __syncthreads();

  const float* wall = W + (DI * 2 + diff) * (256 * 9);

  // Permuted A-row -> kernel map: lane owns two complete 8-k groups.
  // row r holds kernel g*8+k, g = 2*(r>>4)+((r>>2)&1), k = (r&3)+4*((r>>3)&1).
  // c[0..7] -> local kerns 8*hi+0..7 (bin 0..7); c[8..15] -> +16 (bin 8..15).
  const int g_of_r = ((col >> 4) << 1) | ((col >> 2) & 1);
  const int k_of_r = (col & 3) | (((col >> 3) & 1) << 2);
  const int kloc = g_of_r * 8 + k_of_r;

  const f32x16 czero = {};

  for (int kt2 = 0; kt2 < 2; ++kt2) {
    // A fragments for this 32-kern tile (taps padded 9->16 with zeros)
    short8 ah, al;
    {
      const float* wrow = wall + (wave * 64 + kt2 * 32 + kloc) * 9;
      #pragma unroll
      for (int e = 0; e < 8; ++e) {
        int j = hi * 8 + e;
        float wv = (j < 9) ? wrow[j] : 0.f;
        u32 p = bfsplit(wv);
        ah[e] = (short)(p & 0xffffu);
        al[e] = (short)(p >> 16);
      }
    }

    // packed N counters: 8 bins x 8 bits per chunk (max 64/byte: no carry)
    u64 n0 = 0ull, n1 = 0ull;

    #pragma clang loop unroll_count(1)
    for (int tt = 0; tt < 64; ++tt) {
      // B fragment: B[j=8*hi+e][col] = x[tt*32 + col + (j-4)*D]
      const int ebase = PL + tt * 32 + col + (hi * 8 - 4) * D;
      u32 uu[8];
      #pragma unroll
      for (int e = 0; e < 8; ++e) uu[e] = xhl[ebase + e * D];
      union { short8 s; u32 u[4]; } bh, bl;
      #pragma unroll
      for (int p = 0; p < 4; ++p) {
        bh.u[p] = __builtin_amdgcn_perm(uu[2*p+1], uu[2*p], 0x05040100u);
        bl.u[p] = __builtin_amdgcn_perm(uu[2*p+1], uu[2*p], 0x07060302u);
      }

      // (wh+wl)(xh+xl) ~= wl*xh + wh*xl + wh*xh (lo*lo dropped)
      f32x16 c;
      c = MFMA(al, bh.s, czero, 0, 0, 0);
      c = MFMA(ah, bl.s, c,     0, 0, 0);
      c = MFMA(ah, bh.s, c,     0, 0, 0);

      // Embed k-index in low 4 mantissa bits: values become distinct,
      // max/min then carries its own argindex (error <= 16 ulp).
      float cf[16];
      #pragma unroll
      for (int i = 0; i < 16; ++i)
        cf[i] = __uint_as_float((__float_as_uint(c[i]) & 0xFFFFFFF0u) |
                                (u32)(i & 7));

      const float zx0 = max8(cf, 0), zn0 = min8(cf, 0);
      const float zx1 = max8(cf, 8), zn1 = min8(cf, 8);
      const u32 kx0 = __float_as_uint(zx0) & 7u;
      const u32 kx1 = __float_as_uint(zx1) & 7u;

      // M scatter: explicit non-atomic RMW, conflict-free layout
      myM[kx0 * 64]       += zx0;
      myM[(8 + kx1) * 64] += zx1;
      // N scatter: in-register, 8x8-bit packed (4 VALU per count)
      n0 += 1ull << ((__float_as_uint(zn0) & 7u) * 8u);
      n1 += 1ull << ((__float_as_uint(zn1) & 7u) * 8u);
    }

    // stage packed N (one ds_write_b128 per lane)
    {
      uint4 pk;
      pk.x = (u32)n0; pk.y = (u32)(n0 >> 32);
      pk.z = (u32)n1; pk.w = (u32)(n1 >> 32);
      *(uint4*)(nw + (wave * 64 + lane) * 4) = pk;
    }

    // ---- flush: lanes 0..31 reduce M, lanes 32..63 reduce N ----
    // local kern s = 8*hi_s + 16*chunk + k; chunk = s>>4, k = s&7.
    {
      const int s = lane & 31;
      const int hi_s = (s >> 3) & 1;
      if (lane < 32) {
        const int b = ((s >> 4) << 3) | (s & 7);
        const float* src = binsM + wave * 1024 + b * 64 + 32 * hi_s;
        float acc = 0.f;
        #pragma unroll
        for (int c2 = 0; c2 < 32; ++c2) acc += src[(c2 + s) & 31]; // rotated
        fin[((wave * 32 + s) * 2 + kt2) * 2 + 0] = acc;
      } else {
        const int w = ((s >> 4) << 1) | ((s & 7) >> 2);   // packed word index
        const u32 sh = (u32)(s & 3) * 8u;                 // byte within word
        const u32* srcn = nw + wave * 256 + 32 * 4 * hi_s + w;
        u32 acc = 0;
        #pragma unroll
        for (int c2 = 0; c2 < 32; ++c2)
          acc += (srcn[(((c2 + s) & 31)) * 4] >> sh) & 255u;  // rotated
        fin[((wave * 32 + s) * 2 + kt2) * 2 + 1] = (float)acc;
      }
    }

    // rezero own M bins for next round (same-wave DS is in-order: safe)
    if (kt2 == 0) {
      #pragma unroll
      for (int b = 0; b < 16; ++b) myM[b * 64] = 0.f;
    }
  }
  __syncthreads();

  // ---- final: tid = kern (single owner) ----
  const int w2 = tid >> 6, kt2f = (tid >> 5) & 1, r = tid & 31;
  float M = fin[((w2 * 32 + r) * 2 + kt2f) * 2 + 0];
  float N = fin[((w2 * 32 + r) * 2 + kt2f) * 2 + 1];

  if (diff) {
    // remove the spurious t=2047 column (diff branch has 2047 timesteps)
    const float* wrow = wall + tid * 9;
    float z = 0.f;
    #pragma unroll
    for (int j = 0; j < 9; ++j) {
      u32 u = xhl[PL + (LLEN - 1) + (j - 4) * D];
      float xh = __uint_as_float((u & 0xffffu) << 16);
      float xl = __uint_as_float((u >> 16) << 16);
      u32 wp = bfsplit(wrow[j]);
      float wh = __uint_as_float((wp & 0xffffu) << 16);
      float wl = __uint_as_float((wp >> 16) << 16);
      z += wh * xh + wh * xl + wl * xh;
    }
    float* zrow = binsM;               // bins are dead now; reuse as scratch
    zrow[tid] = z;
    __syncthreads();
    const int h8 = tid & ~7;
    float zxv = zrow[h8], znv = zrow[h8];
    #pragma unroll
    for (int j = 1; j < 8; ++j) {
      zxv = fmaxf(zxv, zrow[h8 + j]);
      znv = fminf(znv, zrow[h8 + j]);
    }
    M -= (z == zxv) ? z : 0.f;
    N -= (z == znv) ? 1.f : 0.f;
  }

  const int base = n * FEATS + (DI * 4 + diff * 2) * 256 + tid;
  out[base]       = M > 0.f ? sqrtf(M) : 0.f;    // count_max
  out[base + 256] = N > 0.f ? sqrtf(N) : 0.f;    // count_min
}

__global__ __launch_bounds__(256, 3) void hydra_kernel(
    const float* __restrict__ X, const float* __restrict__ W,
    float* __restrict__ out)
{
  __shared__ u32   xhl[XSZ];               // 16 KB packed bf16 hi|lo
  __shared__ float binsM[4 * 16 * 64];     // 16 KB [wave][bin][lane]
  __shared__ u32   nw[4 * 64 * 4];         // 4 KB packed N staging
  __shared__ float fin[512];               // 2 KB: [4][32][2]{M,N}
  // total 38912 B <= 40960 -> 4 blocks/CU
  switch (blockIdx.z) {
    case 0: body<1,   0>(X, W, out, xhl, binsM, nw, fin); break;
    case 1: body<2,   1>(X, W, out, xhl, binsM, nw, fin); break;
    case 2: body<4,   2>(X, W, out, xhl, binsM, nw, fin); break;
    case 3: body<8,   3>(X, W, out, xhl, binsM, nw, fin); break;
    case 4: body<16,  4>(X, W, out, xhl, binsM, nw, fin); break;
    case 5: body<32,  5>(X, W, out, xhl, binsM, nw, fin); break;
    case 6: body<64,  6>(X, W, out, xhl, binsM, nw, fin); break;
    case 7: body<128, 7>(X, W, out, xhl, binsM, nw, fin); break;
  }
}

} // namespace

extern "C" void kernel_launch(void* const* d_in, const int* in_sizes, int n_in,
                              void* d_out, int out_size, void* d_ws, size_t ws_size,
                              hipStream_t stream) {
  const float* X = (const float*)d_in[0];
  const float* W = (const float*)d_in[1];
  float* out = (float*)d_out;
  dim3 grid(NEX, 2, 8);
  hipLaunchKernelGGL(hydra_kernel, grid, dim3(256), 0, stream, X, W, out);
}

// Round 15
// 266.996 us; speedup vs baseline: 10.3280x; 1.0619x over previous
//
#include <hip/hip_runtime.h>
#include <math.h>

namespace {

typedef short short8 __attribute__((ext_vector_type(8)));
typedef float f32x16 __attribute__((ext_vector_type(16)));
typedef unsigned int u32;
typedef unsigned long long u64;

constexpr int NEX = 256, LLEN = 2048, FEATS = 8192;
constexpr int PL = 512;          // 4*Dmax zeros on the left
constexpr int XSZ = 4096;

// packed bf16 split: (lo_bf16 << 16) | hi_bf16, both RNE
__device__ __forceinline__ u32 bfsplit(float x) {
  u32 b = __float_as_uint(x);
  u32 hb = (b + 0x7fffu + ((b >> 16) & 1u)) >> 16;
  float lo = x - __uint_as_float(hb << 16);
  u32 b2 = __float_as_uint(lo);
  u32 lb = (b2 + 0x7fffu + ((b2 >> 16) & 1u)) >> 16;
  return hb | (lb << 16);
}

__device__ __forceinline__ float max8(const float* v, int o) {
  float m0 = fmaxf(fmaxf(v[o+0], v[o+1]), v[o+2]);
  float m1 = fmaxf(fmaxf(v[o+3], v[o+4]), v[o+5]);
  float m2 = fmaxf(v[o+6], v[o+7]);
  return fmaxf(fmaxf(m0, m1), m2);
}
__device__ __forceinline__ float min8(const float* v, int o) {
  float m0 = fminf(fminf(v[o+0], v[o+1]), v[o+2]);
  float m1 = fminf(fminf(v[o+3], v[o+4]), v[o+5]);
  float m2 = fminf(v[o+6], v[o+7]);
  return fminf(fminf(m0, m1), m2);
}

#define MFMA __builtin_amdgcn_mfma_f32_32x32x16_bf16

template<int D, int DI>
__device__ __forceinline__ void body(
    const float* __restrict__ X, const float* __restrict__ W,
    float* __restrict__ out, u32* __restrict__ xhl,
    float* __restrict__ binsM, float* __restrict__ fin)
{
  const int n = blockIdx.x, diff = blockIdx.y, tid = threadIdx.x;
  const int lane = tid & 63, wave = tid >> 6;
  const int col = lane & 31, hi = lane >> 5;

  // ---- stage padded input as packed bf16 hi/lo (diff on the fly) ----
  const float* xr = X + n * LLEN;
  for (int i = tid; i < XSZ; i += 256) {
    float x = 0.f;
    if (diff) { if (i >= PL && i < PL + LLEN - 1) x = xr[i - PL + 1] - xr[i - PL]; }
    else      { if (i >= PL && i < PL + LLEN)     x = xr[i - PL]; }
    xhl[i] = bfsplit(x);
  }

  // ---- lane-private M bins, bank-invariant layout [wave][bin 0..31][lane]
  // bins 0..15: kt2=0, bins 16..31: kt2=1. bank = lane%32 always: free.
  float* myM = binsM + wave * 2048 + lane;
  #pragma unroll
  for (int b = 0; b < 32; ++b) myM[b * 64] = 0.f;
  __syncthreads();

  const float* wall = W + (DI * 2 + diff) * (256 * 9);

  // Permuted A-row -> kernel map: lane owns two complete 8-k groups.
  // row r holds kernel g*8+k, g = 2*(r>>4)+((r>>2)&1), k = (r&3)+4*((r>>3)&1).
  const int g_of_r = ((col >> 4) << 1) | ((col >> 2) & 1);
  const int k_of_r = (col & 3) | (((col >> 3) & 1) << 2);
  const int kloc = g_of_r * 8 + k_of_r;

  // A fragments for BOTH 32-kern tiles (taps padded 9->16 with zeros)
  short8 ah0, al0, ah1, al1;
  {
    const float* w0 = wall + (wave * 64 + kloc) * 9;
    const float* w1 = w0 + 288;                    // +32 kernels
    #pragma unroll
    for (int e = 0; e < 8; ++e) {
      int j = hi * 8 + e;
      float v0 = (j < 9) ? w0[j] : 0.f;
      float v1 = (j < 9) ? w1[j] : 0.f;
      u32 p0 = bfsplit(v0), p1 = bfsplit(v1);
      ah0[e] = (short)(p0 & 0xffffu); al0[e] = (short)(p0 >> 16);
      ah1[e] = (short)(p1 & 0xffffu); al1[e] = (short)(p1 >> 16);
    }
  }

  const f32x16 czero = {};
  // packed N counters: 8 bins x 8 bits; (kt2, chunk) -> one u64 each
  u64 n00 = 0ull, n01 = 0ull, n10 = 0ull, n11 = 0ull;

  #pragma clang loop unroll_count(1)
  for (int tt = 0; tt < 64; ++tt) {
    // B fragment (shared by both kt2): B[j=8*hi+e][col] = x[tt*32+col+(j-4)*D]
    // pair-base form: offsets {0, D} dwords fit ds_read2_b32 for all D<=128.
    const int ebase = PL + tt * 32 + col + (hi * 8 - 4) * D;
    u32 uu[8];
    #pragma unroll
    for (int p = 0; p < 4; ++p) {
      const u32* bp = xhl + (ebase + p * 2 * D);
      uu[2*p]   = bp[0];
      uu[2*p+1] = bp[D];
    }
    union { short8 s; u32 u[4]; } bh, bl;
    #pragma unroll
    for (int p = 0; p < 4; ++p) {
      bh.u[p] = __builtin_amdgcn_perm(uu[2*p+1], uu[2*p], 0x05040100u);
      bl.u[p] = __builtin_amdgcn_perm(uu[2*p+1], uu[2*p], 0x07060302u);
    }

    {   // ---- kern tile kt2 = 0 ----
      f32x16 c;
      c = MFMA(al0, bh.s, czero, 0, 0, 0);
      c = MFMA(ah0, bl.s, c,     0, 0, 0);
      c = MFMA(ah0, bh.s, c,     0, 0, 0);
      float cf[16];
      #pragma unroll
      for (int i = 0; i < 16; ++i)
        cf[i] = __uint_as_float((__float_as_uint(c[i]) & 0xFFFFFFF0u) |
                                (u32)(i & 7));
      const float zx0 = max8(cf, 0), zn0 = min8(cf, 0);
      const float zx1 = max8(cf, 8), zn1 = min8(cf, 8);
      myM[(__float_as_uint(zx0) & 7u) * 64]       += zx0;
      myM[(8u + (__float_as_uint(zx1) & 7u)) * 64] += zx1;
      n00 += 1ull << ((__float_as_uint(zn0) & 7u) * 8u);
      n01 += 1ull << ((__float_as_uint(zn1) & 7u) * 8u);
    }
    {   // ---- kern tile kt2 = 1 (same B!) ----
      f32x16 c;
      c = MFMA(al1, bh.s, czero, 0, 0, 0);
      c = MFMA(ah1, bl.s, c,     0, 0, 0);
      c = MFMA(ah1, bh.s, c,     0, 0, 0);
      float cf[16];
      #pragma unroll
      for (int i = 0; i < 16; ++i)
        cf[i] = __uint_as_float((__float_as_uint(c[i]) & 0xFFFFFFF0u) |
                                (u32)(i & 7));
      const float zx0 = max8(cf, 0), zn0 = min8(cf, 0);
      const float zx1 = max8(cf, 8), zn1 = min8(cf, 8);
      myM[(16u + (__float_as_uint(zx0) & 7u)) * 64] += zx0;
      myM[(24u + (__float_as_uint(zx1) & 7u)) * 64] += zx1;
      n10 += 1ull << ((__float_as_uint(zn0) & 7u) * 8u);
      n11 += 1ull << ((__float_as_uint(zn1) & 7u) * 8u);
    }
  }

  // ---- single flush: lane = local kern s2 (0..63) of this wave ----
  // s2 = kt2*32 + s; s = 8*hi_s + 16*chunk + k.
  const int kt2f = lane >> 5;
  const int s = lane & 31;
  const int hi_s = (s >> 3) & 1;
  const int chunk = s >> 4;
  const int kk = s & 7;
  float accM = 0.f;
  {
    const int b = kt2f * 16 + chunk * 8 + kk;
    const float* src = binsM + wave * 2048 + b * 64 + 32 * hi_s;
    #pragma unroll
    for (int c2 = 0; c2 < 32; ++c2) accM += src[(c2 + s) & 31];  // rotated
  }
  __syncthreads();   // fence: M reads complete before u32 staging overwrites

  // N staging into own (now dead) bins region: layout [word 0..7][lane]
  u32* nwp = (u32*)(binsM + wave * 2048);
  nwp[0 * 64 + lane] = (u32)n00; nwp[1 * 64 + lane] = (u32)(n00 >> 32);
  nwp[2 * 64 + lane] = (u32)n01; nwp[3 * 64 + lane] = (u32)(n01 >> 32);
  nwp[4 * 64 + lane] = (u32)n10; nwp[5 * 64 + lane] = (u32)(n10 >> 32);
  nwp[6 * 64 + lane] = (u32)n11; nwp[7 * 64 + lane] = (u32)(n11 >> 32);
  float accN;
  {
    const int w2 = kt2f * 4 + chunk * 2 + (kk >> 2);
    const u32 sh = (u32)(kk & 3) * 8u;
    const u32* srcn = nwp + w2 * 64 + 32 * hi_s;
    u32 a = 0;
    #pragma unroll
    for (int c2 = 0; c2 < 32; ++c2)
      a += (srcn[(c2 + s) & 31] >> sh) & 255u;                   // rotated
    accN = (float)a;
  }
  *(float2*)(fin + (wave * 64 + lane) * 2) = make_float2(accM, accN);
  __syncthreads();

  // ---- final: tid = kern (single owner) ----
  float2 mn2 = *(const float2*)(fin + tid * 2);
  float M = mn2.x, N = mn2.y;

  if (diff) {
    // remove the spurious t=2047 column (diff branch has 2047 timesteps)
    const float* wrow = wall + tid * 9;
    float z = 0.f;
    #pragma unroll
    for (int j = 0; j < 9; ++j) {
      u32 u = xhl[PL + (LLEN - 1) + (j - 4) * D];
      float xh = __uint_as_float((u & 0xffffu) << 16);
      float xl = __uint_as_float((u >> 16) << 16);
      u32 wp = bfsplit(wrow[j]);
      float wh = __uint_as_float((wp & 0xffffu) << 16);
      float wl = __uint_as_float((wp >> 16) << 16);
      z += wh * xh + wh * xl + wl * xh;
    }
    float* zrow = binsM;               // bins dead; barrier above fences reuse
    zrow[tid] = z;
    __syncthreads();
    const int h8 = tid & ~7;
    float zxv = zrow[h8], znv = zrow[h8];
    #pragma unroll
    for (int j = 1; j < 8; ++j) {
      zxv = fmaxf(zxv, zrow[h8 + j]);
      znv = fminf(znv, zrow[h8 + j]);
    }
    M -= (z == zxv) ? z : 0.f;
    N -= (z == znv) ? 1.f : 0.f;
  }

  const int base = n * FEATS + (DI * 4 + diff * 2) * 256 + tid;
  out[base]       = M > 0.f ? sqrtf(M) : 0.f;    // count_max
  out[base + 256] = N > 0.f ? sqrtf(N) : 0.f;    // count_min
}

__global__ __launch_bounds__(256, 3) void hydra_kernel(
    const float* __restrict__ X, const float* __restrict__ W,
    float* __restrict__ out)
{
  __shared__ u32   xhl[XSZ];               // 16 KB packed bf16 hi|lo
  __shared__ float binsM[4 * 32 * 64];     // 32 KB [wave][bin][lane], both kt2
  __shared__ float fin[512];               // 2 KB: [4][64]{M,N}
  // total 51200 B <= 54613 -> 3 blocks/CU
  switch (blockIdx.z) {
    case 0: body<1,   0>(X, W, out, xhl, binsM, fin); break;
    case 1: body<2,   1>(X, W, out, xhl, binsM, fin); break;
    case 2: body<4,   2>(X, W, out, xhl, binsM, fin); break;
    case 3: body<8,   3>(X, W, out, xhl, binsM, fin); break;
    case 4: body<16,  4>(X, W, out, xhl, binsM, fin); break;
    case 5: body<32,  5>(X, W, out, xhl, binsM, fin); break;
    case 6: body<64,  6>(X, W, out, xhl, binsM, fin); break;
    case 7: body<128, 7>(X, W, out, xhl, binsM, fin); break;
  }
}

} // namespace

extern "C" void kernel_launch(void* const* d_in, const int* in_sizes, int n_in,
                              void* d_out, int out_size, void* d_ws, size_t ws_size,
                              hipStream_t stream) {
  const float* X = (const float*)d_in[0];
  const float* W = (const float*)d_in[1];
  float* out = (float*)d_out;
  dim3 grid(NEX, 2, 8);
  hipLaunchKernelGGL(hydra_kernel, grid, dim3(256), 0, stream, X, W, out);
}

// Round 16
// 263.667 us; speedup vs baseline: 10.4584x; 1.0126x over previous
//
#include <hip/hip_runtime.h>
#include <math.h>

namespace {

typedef short short8 __attribute__((ext_vector_type(8)));
typedef float f32x16 __attribute__((ext_vector_type(16)));
typedef unsigned int u32;
typedef unsigned long long u64;

constexpr int NEX = 256, LLEN = 2048, FEATS = 8192;
constexpr int PL = 512;          // 4*Dmax zeros on the left
constexpr int XSZ = 4096;

// packed bf16 split: (lo_bf16 << 16) | hi_bf16, both RNE
__device__ __forceinline__ u32 bfsplit(float x) {
  u32 b = __float_as_uint(x);
  u32 hb = (b + 0x7fffu + ((b >> 16) & 1u)) >> 16;
  float lo = x - __uint_as_float(hb << 16);
  u32 b2 = __float_as_uint(lo);
  u32 lb = (b2 + 0x7fffu + ((b2 >> 16) & 1u)) >> 16;
  return hb | (lb << 16);
}

__device__ __forceinline__ float max8(const float* v, int o) {
  float m0 = fmaxf(fmaxf(v[o+0], v[o+1]), v[o+2]);
  float m1 = fmaxf(fmaxf(v[o+3], v[o+4]), v[o+5]);
  float m2 = fmaxf(v[o+6], v[o+7]);
  return fmaxf(fmaxf(m0, m1), m2);
}
__device__ __forceinline__ float min8(const float* v, int o) {
  float m0 = fminf(fminf(v[o+0], v[o+1]), v[o+2]);
  float m1 = fminf(fminf(v[o+3], v[o+4]), v[o+5]);
  float m2 = fminf(v[o+6], v[o+7]);
  return fminf(fminf(m0, m1), m2);
}

#define MFMA __builtin_amdgcn_mfma_f32_32x32x16_bf16

template<int D, int DI>
__device__ __forceinline__ void body(
    const float* __restrict__ X, const float* __restrict__ W,
    float* __restrict__ out, u32* __restrict__ xhl,
    float* __restrict__ binsM, float* __restrict__ fin)
{
  const int n = blockIdx.x, diff = blockIdx.y, tid = threadIdx.x;
  const int lane = tid & 63, wave = tid >> 6;
  const int col = lane & 31, hi = lane >> 5;

  // ---- stage padded input as packed bf16 hi/lo (diff on the fly) ----
  const float* xr = X + n * LLEN;
  for (int i = tid; i < XSZ; i += 256) {
    float x = 0.f;
    if (diff) { if (i >= PL && i < PL + LLEN - 1) x = xr[i - PL + 1] - xr[i - PL]; }
    else      { if (i >= PL && i < PL + LLEN)     x = xr[i - PL]; }
    xhl[i] = bfsplit(x);
  }

  // ---- lane-private M bins, bank-invariant layout [wave][bin 0..31][lane]
  float* myM = binsM + wave * 2048 + lane;
  #pragma unroll
  for (int b = 0; b < 32; ++b) myM[b * 64] = 0.f;
  __syncthreads();

  const float* wall = W + (DI * 2 + diff) * (256 * 9);

  // Permuted A-row -> kernel map: lane owns two complete 8-k groups.
  const int g_of_r = ((col >> 4) << 1) | ((col >> 2) & 1);
  const int k_of_r = (col & 3) | (((col >> 3) & 1) << 2);
  const int kloc = g_of_r * 8 + k_of_r;

  // A fragments for BOTH 32-kern tiles (taps padded 9->16 with zeros)
  short8 ah0, al0, ah1, al1;
  {
    const float* w0 = wall + (wave * 64 + kloc) * 9;
    const float* w1 = w0 + 288;
    #pragma unroll
    for (int e = 0; e < 8; ++e) {
      int j = hi * 8 + e;
      float v0 = (j < 9) ? w0[j] : 0.f;
      float v1 = (j < 9) ? w1[j] : 0.f;
      u32 p0 = bfsplit(v0), p1 = bfsplit(v1);
      ah0[e] = (short)(p0 & 0xffffu); al0[e] = (short)(p0 >> 16);
      ah1[e] = (short)(p1 & 0xffffu); al1[e] = (short)(p1 >> 16);
    }
  }

  const f32x16 czero = {};
  u64 n00 = 0ull, n01 = 0ull, n10 = 0ull, n11 = 0ull;

  // epilogue for one MFMA result: embed index, trees, M-RMW, N-count
  #define EPI(c, BOFF, NA, NB)                                               \
    {                                                                        \
      float cf[16];                                                          \
      _Pragma("unroll")                                                      \
      for (int i = 0; i < 16; ++i)                                           \
        cf[i] = __uint_as_float((__float_as_uint(c[i]) & 0xFFFFFFF0u) |      \
                                (u32)(i & 7));                               \
      const float zx0 = max8(cf, 0), zn0 = min8(cf, 0);                      \
      const float zx1 = max8(cf, 8), zn1 = min8(cf, 8);                      \
      myM[((BOFF) + (__float_as_uint(zx0) & 7u)) * 64] += zx0;               \
      myM[((BOFF) + 8u + (__float_as_uint(zx1) & 7u)) * 64] += zx1;          \
      NA += 1ull << ((__float_as_uint(zn0) & 7u) * 8u);                      \
      NB += 1ull << ((__float_as_uint(zn1) & 7u) * 8u);                      \
    }

  // 2x unrolled tt loop: batch-issue BOTH B fragments' ds_reads up front so
  // compute of pair A covers pair B's LDS latency.
  #pragma clang loop unroll_count(1)
  for (int tt2 = 0; tt2 < 32; ++tt2) {
    const int ebaseA = PL + (tt2 * 2) * 32 + col + (hi * 8 - 4) * D;
    u32 uA[8], uB[8];
    #pragma unroll
    for (int p = 0; p < 4; ++p) {
      const u32* bp = xhl + (ebaseA + p * 2 * D);
      uA[2*p]   = bp[0];
      uA[2*p+1] = bp[D];
      uB[2*p]   = bp[32];        // ttB = ttA+1: +32 elements
      uB[2*p+1] = bp[D + 32];
    }
    union { short8 s; u32 u[4]; } bhA, blA, bhB, blB;
    #pragma unroll
    for (int p = 0; p < 4; ++p) {
      bhA.u[p] = __builtin_amdgcn_perm(uA[2*p+1], uA[2*p], 0x05040100u);
      blA.u[p] = __builtin_amdgcn_perm(uA[2*p+1], uA[2*p], 0x07060302u);
      bhB.u[p] = __builtin_amdgcn_perm(uB[2*p+1], uB[2*p], 0x05040100u);
      blB.u[p] = __builtin_amdgcn_perm(uB[2*p+1], uB[2*p], 0x07060302u);
    }

    {   // ttA, kt2 = 0
      f32x16 c;
      c = MFMA(al0, bhA.s, czero, 0, 0, 0);
      c = MFMA(ah0, blA.s, c,     0, 0, 0);
      c = MFMA(ah0, bhA.s, c,     0, 0, 0);
      EPI(c, 0u, n00, n01)
    }
    {   // ttA, kt2 = 1
      f32x16 c;
      c = MFMA(al1, bhA.s, czero, 0, 0, 0);
      c = MFMA(ah1, blA.s, c,     0, 0, 0);
      c = MFMA(ah1, bhA.s, c,     0, 0, 0);
      EPI(c, 16u, n10, n11)
    }
    {   // ttB, kt2 = 0
      f32x16 c;
      c = MFMA(al0, bhB.s, czero, 0, 0, 0);
      c = MFMA(ah0, blB.s, c,     0, 0, 0);
      c = MFMA(ah0, bhB.s, c,     0, 0, 0);
      EPI(c, 0u, n00, n01)
    }
    {   // ttB, kt2 = 1
      f32x16 c;
      c = MFMA(al1, bhB.s, czero, 0, 0, 0);
      c = MFMA(ah1, blB.s, c,     0, 0, 0);
      c = MFMA(ah1, bhB.s, c,     0, 0, 0);
      EPI(c, 16u, n10, n11)
    }
  }
  #undef EPI

  // ---- single flush: lane = local kern s2 (0..63) of this wave ----
  const int kt2f = lane >> 5;
  const int s = lane & 31;
  const int hi_s = (s >> 3) & 1;
  const int chunk = s >> 4;
  const int kk = s & 7;
  float accM = 0.f;
  {
    const int b = kt2f * 16 + chunk * 8 + kk;
    const float* src = binsM + wave * 2048 + b * 64 + 32 * hi_s;
    #pragma unroll
    for (int c2 = 0; c2 < 32; ++c2) accM += src[(c2 + s) & 31];  // rotated
  }
  __syncthreads();   // fence: M reads complete before u32 staging overwrites

  // N staging into own (now dead) bins region: layout [word 0..7][lane]
  u32* nwp = (u32*)(binsM + wave * 2048);
  nwp[0 * 64 + lane] = (u32)n00; nwp[1 * 64 + lane] = (u32)(n00 >> 32);
  nwp[2 * 64 + lane] = (u32)n01; nwp[3 * 64 + lane] = (u32)(n01 >> 32);
  nwp[4 * 64 + lane] = (u32)n10; nwp[5 * 64 + lane] = (u32)(n10 >> 32);
  nwp[6 * 64 + lane] = (u32)n11; nwp[7 * 64 + lane] = (u32)(n11 >> 32);
  float accN;
  {
    const int w2 = kt2f * 4 + chunk * 2 + (kk >> 2);
    const u32 sh = (u32)(kk & 3) * 8u;
    const u32* srcn = nwp + w2 * 64 + 32 * hi_s;
    u32 a = 0;
    #pragma unroll
    for (int c2 = 0; c2 < 32; ++c2)
      a += (srcn[(c2 + s) & 31] >> sh) & 255u;                   // rotated
    accN = (float)a;
  }
  *(float2*)(fin + (wave * 64 + lane) * 2) = make_float2(accM, accN);
  __syncthreads();

  // ---- final: tid = kern (single owner) ----
  float2 mn2 = *(const float2*)(fin + tid * 2);
  float M = mn2.x, N = mn2.y;

  if (diff) {
    // remove the spurious t=2047 column (diff branch has 2047 timesteps)
    const float* wrow = wall + tid * 9;
    float z = 0.f;
    #pragma unroll
    for (int j = 0; j < 9; ++j) {
      u32 u = xhl[PL + (LLEN - 1) + (j - 4) * D];
      float xh = __uint_as_float((u & 0xffffu) << 16);
      float xl = __uint_as_float((u >> 16) << 16);
      u32 wp = bfsplit(wrow[j]);
      float wh = __uint_as_float((wp & 0xffffu) << 16);
      float wl = __uint_as_float((wp >> 16) << 16);
      z += wh * xh + wh * xl + wl * xh;
    }
    float* zrow = binsM;               // bins dead; barrier above fences reuse
    zrow[tid] = z;
    __syncthreads();
    const int h8 = tid & ~7;
    float zxv = zrow[h8], znv = zrow[h8];
    #pragma unroll
    for (int j = 1; j < 8; ++j) {
      zxv = fmaxf(zxv, zrow[h8 + j]);
      znv = fminf(znv, zrow[h8 + j]);
    }
    M -= (z == zxv) ? z : 0.f;
    N -= (z == znv) ? 1.f : 0.f;
  }

  const int base = n * FEATS + (DI * 4 + diff * 2) * 256 + tid;
  out[base]       = M > 0.f ? sqrtf(M) : 0.f;    // count_max
  out[base + 256] = N > 0.f ? sqrtf(N) : 0.f;    // count_min
}

__global__ __launch_bounds__(256, 3) void hydra_kernel(
    const float* __restrict__ X, const float* __restrict__ W,
    float* __restrict__ out)
{
  __shared__ u32   xhl[XSZ];               // 16 KB packed bf16 hi|lo
  __shared__ float binsM[4 * 32 * 64];     // 32 KB [wave][bin][lane], both kt2
  __shared__ float fin[512];               // 2 KB: [4][64]{M,N}
  // total 51200 B <= 54613 -> 3 blocks/CU
  switch (blockIdx.z) {
    case 0: body<1,   0>(X, W, out, xhl, binsM, fin); break;
    case 1: body<2,   1>(X, W, out, xhl, binsM, fin); break;
    case 2: body<4,   2>(X, W, out, xhl, binsM, fin); break;
    case 3: body<8,   3>(X, W, out, xhl, binsM, fin); break;
    case 4: body<16,  4>(X, W, out, xhl, binsM, fin); break;
    case 5: body<32,  5>(X, W, out, xhl, binsM, fin); break;
    case 6: body<64,  6>(X, W, out, xhl, binsM, fin); break;
    case 7: body<128, 7>(X, W, out, xhl, binsM, fin); break;
  }
}

} // namespace

extern "C" void kernel_launch(void* const* d_in, const int* in_sizes, int n_in,
                              void* d_out, int out_size, void* d_ws, size_t ws_size,
                              hipStream_t stream) {
  const float* X = (const float*)d_in[0];
  const float* W = (const float*)d_in[1];
  float* out = (float*)d_out;
  dim3 grid(NEX, 2, 8);
  hipLaunchKernelGGL(hydra_kernel, grid, dim3(256), 0, stream, X, W, out);
}